// Round 11
// baseline (703.394 us; speedup 1.0000x reference)
//
#include <hip/hip_runtime.h>
#include <hip/hip_bf16.h>

typedef __attribute__((ext_vector_type(8))) short bf16x8;
typedef __attribute__((ext_vector_type(4))) short bf16x4;
typedef __attribute__((ext_vector_type(4))) float f32x4;
typedef __attribute__((ext_vector_type(2))) float f32x2;

#define NPEDS 65536
#define SEQ 12
#define HD 128
#define ED 64
#define MBLK 256  // peds per block: 8 waves x 32 peds (2 ped-tiles of 16)
#define WHH_FRAGS 128
#define WEFF_FRAGS 132  // 128 gate frags + 4 w_hp frags
#define NFRAGS (WHH_FRAGS + WEFF_FRAGS)
#define L2E 1.44269504088896340736f
#define NEG2L (-2.88539008177792681472f)
// float tail after frags: beff[512], b0eff[512], w2[1024]

__device__ __forceinline__ short f2bf(float x) {
  __hip_bfloat16 b = __float2bfloat16(x);  // RNE
  return __builtin_bit_cast(short, b);
}
__device__ __forceinline__ float exp2_(float x) {
#if __has_builtin(__builtin_amdgcn_exp2f)
  return __builtin_amdgcn_exp2f(x);
#else
  return exp2f(x);
#endif
}

// Gate rows PRE-SCALED by log2e (2*log2e for gate g; torch order i,f,g,o):
// sigm(x)=rcp(1+exp2(-y)); tanh(g)=(2-R)/R, R=1+exp2(-yg).
// wsB layout (shorts):
//  [0, 128*512):         step-0 frags (w_hh, scaled), frag = (c*4+g)*4+kt
//  [128*512, 256*512):   W_eff gate frags (scaled),   frag = (c*4+g)*4+kt
//  [256*512, 260*512):   w_hp rel frags (UNscaled),   frag = kt
//  float tail fl[]: fl[0:512) beff, fl[512:1024) b0eff, fl[1024:2048) w2[n][2]
__global__ void prep_kernel(const float* __restrict__ w_ih,
                            const float* __restrict__ w_hh,
                            const float* __restrict__ w_se,
                            const float* __restrict__ w_hp,
                            const float* __restrict__ b_ih,
                            const float* __restrict__ b_hh,
                            const float* __restrict__ b_se,
                            const float* __restrict__ b_hp,
                            short* __restrict__ wsB, float* __restrict__ fl) {
  int t = blockIdx.x * 256 + threadIdx.x;
  if (t < WHH_FRAGS * 64) {
    int frag = t >> 6, l = t & 63;
    int cc = frag >> 4, g = (frag >> 2) & 3, kt = frag & 3;
    float fac = (g == 2) ? 2.0f * L2E : L2E;
    int n = g * HD + cc * 16 + (l & 15);
    bf16x8 v;
#pragma unroll
    for (int e = 0; e < 8; ++e) {
      int k = kt * 32 + ((l >> 4) << 2) + (e & 3) + ((e >> 2) << 4);
      v[e] = f2bf(w_hh[n * HD + k] * fac);
    }
    *(bf16x8*)(wsB + (size_t)frag * 512 + l * 8) = v;
  } else if (t < NFRAGS * 64) {
    int u = t - WHH_FRAGS * 64;
    int frag = u >> 6, l = u & 63;
    int llo = l & 15;
    int ks[8];
#pragma unroll
    for (int e = 0; e < 8; ++e)
      ks[e] = (frag & 3) * 32 + ((l >> 4) << 2) + (e & 3) + ((e >> 2) << 4);
    float acc[8];
    if (frag < 128) {
      int cc = frag >> 4, g = (frag >> 2) & 3;
      float fac = (g == 2) ? 2.0f * L2E : L2E;
      int n = g * HD + cc * 16 + llo;
#pragma unroll
      for (int e = 0; e < 8; ++e) acc[e] = w_hh[n * HD + ks[e]];
      for (int j = 0; j < ED; ++j) {
        float wij = w_ih[n * ED + j];
        float se0 = w_se[2 * j], se1 = w_se[2 * j + 1];
#pragma unroll
        for (int e = 0; e < 8; ++e)
          acc[e] += wij * (se0 * w_hp[ks[e]] + se1 * w_hp[HD + ks[e]]);
      }
#pragma unroll
      for (int e = 0; e < 8; ++e) acc[e] *= fac;
    } else {
#pragma unroll
      for (int e = 0; e < 8; ++e)
        acc[e] = (llo < 2) ? w_hp[llo * HD + ks[e]] : 0.f;
    }
    bf16x8 v;
#pragma unroll
    for (int e = 0; e < 8; ++e) v[e] = f2bf(acc[e]);
    *(bf16x8*)(wsB + (size_t)(WHH_FRAGS + frag) * 512 + l * 8) = v;
  } else if (t < NFRAGS * 64 + 512) {
    int n = t - NFRAGS * 64;
    float fac = ((n >> 7) == 2) ? 2.0f * L2E : L2E;
    float b = b_ih[n] + b_hh[n];
    float s0 = 0.f, w20 = 0.f, w21 = 0.f;
    for (int j = 0; j < ED; ++j) {
      float wij = w_ih[n * ED + j];
      s0 += wij * b_se[j];
      w20 += wij * w_se[2 * j];
      w21 += wij * w_se[2 * j + 1];
    }
    fl[n] = fac * (b + s0 + w20 * b_hp[0] + w21 * b_hp[1]);  // beff (s>=1)
    fl[512 + n] = fac * (b + s0);                            // b0eff (step 0)
    fl[1024 + 2 * n] = fac * w20;  // w2 = w_ih @ w_se (scaled)
    fl[1024 + 2 * n + 1] = fac * w21;
  }
}

// BARRIER-FREE RECURRENCE. Each wave owns 32 peds (2 ped-tiles of 16) and
// computes ALL 512 gate cols for them; weights live in LDS (shared, 128 KB),
// h and c live in REGISTERS. The swapped-operand C-layout (ped=llo,
// col=lhi*4+r) feeds the next step's B-fragments in the SAME lane (proven by
// R8's LDS roundtrip with identical mapping) -> in-register repack, zero
// cross-wave communication, zero barriers in the 12-step loop.
// launch_bounds(512,2): cap 256, live ~200 -- spill-safe. 1 block/CU (LDS).
__global__ __launch_bounds__(512, 2) void lstm_kernel(
    const float* __restrict__ lpr, const float* __restrict__ h0,
    const float* __restrict__ c0, const float* __restrict__ b_hp,
    const short* __restrict__ wsB, const float* __restrict__ fl,
    float* __restrict__ out) {
  __shared__ __align__(16) short s_w[WHH_FRAGS * 512];  // 128 KB weight frags
  __shared__ __align__(16) short s_whp[4 * 512];        // 4 KB w_hp frags
  __shared__ __align__(16) float s_beff[512];           // 2 KB folded bias

  const int tid = threadIdx.x;
  const int l = tid & 63;
  const int lhi = l >> 4;
  const int llo = l & 15;
  const int pbase = blockIdx.x * MBLK + (tid >> 6) * 32;
  const int ped0 = pbase + llo;       // Pt=0 ped for this lane
  const int ped1 = pbase + 16 + llo;  // Pt=1 ped

  // stage w_hh frags (131072 B) for step 0
  {
    const f32x4* src = (const f32x4*)wsB;
    f32x4* dst = (f32x4*)s_w;
#pragma unroll
    for (int i = 0; i < 16; ++i) dst[i * 512 + tid] = src[i * 512 + tid];
  }
  if (tid < 256)
    ((f32x4*)s_whp)[tid] =
        ((const f32x4*)(wsB + (size_t)(WHH_FRAGS + 128) * 512))[tid];
  s_beff[tid] = fl[tid];

  // c-state in registers: creg[Pt][c][r] = c0[ped][c*16 + lhi*4 + r]
  f32x4 creg[2][8];
#pragma unroll
  for (int Pt = 0; Pt < 2; ++Pt)
#pragma unroll
    for (int c = 0; c < 8; ++c)
      creg[Pt][c] = *(const f32x4*)&c0[(size_t)(pbase + Pt * 16 + llo) * HD +
                                       c * 16 + lhi * 4];

  // h-state as B-fragments in registers (k = kt*32 + lhi*4 + (e&3) + 16(e>>2))
  bf16x8 Bh[2][4];
#pragma unroll
  for (int Pt = 0; Pt < 2; ++Pt)
#pragma unroll
    for (int kt = 0; kt < 4; ++kt) {
      const float* hp = &h0[(size_t)(pbase + Pt * 16 + llo) * HD + kt * 32 +
                            lhi * 4];
      f32x4 lo = *(const f32x4*)hp;
      f32x4 hi = *(const f32x4*)(hp + 16);
      bf16x4 a, b;
      a[0] = f2bf(lo[0]); a[1] = f2bf(lo[1]);
      a[2] = f2bf(lo[2]); a[3] = f2bf(lo[3]);
      b[0] = f2bf(hi[0]); b[1] = f2bf(hi[1]);
      b[2] = f2bf(hi[2]); b[3] = f2bf(hi[3]);
      Bh[Pt][kt] = __builtin_shufflevector(a, b, 0, 1, 2, 3, 4, 5, 6, 7);
    }
  const float bhp0 = b_hp[0], bhp1 = b_hp[1];
  __syncthreads();

  // 7-trans nonlinearity for one ped-tile chunk; returns 4 bf16 h values
  auto nonlin = [&](f32x4 (&acc)[4], f32x4& cr) -> bf16x4 {
    bf16x4 h4;
#pragma unroll
    for (int r = 0; r < 4; ++r) {
      float Q = 1.f + exp2_(-acc[0][r]);  // i
      float P = 1.f + exp2_(-acc[1][r]);  // f
      float R = 1.f + exp2_(-acc[2][r]);  // g
      float QR = Q * R;
      float rD = __builtin_amdgcn_rcpf(P * QR);
      float cn = (cr[r] * QR + (2.f - R) * P) * rD;
      cr[r] = cn;
      float T = 1.f + exp2_(cn * NEG2L);
      float S = 1.f + exp2_(-acc[3][r]);  // o
      h4[r] = f2bf((2.f - T) * __builtin_amdgcn_rcpf(S * T));
    }
    return h4;
  };
  // rel(t) = h(t+1) @ w_hp^T + b_hp for both ped-tiles; coalesced f32x2 out
  auto rel_do = [&](bf16x8 (&BhN)[2][4], int t) {
#pragma unroll
    for (int Pt = 0; Pt < 2; ++Pt) {
      f32x4 ar = {lhi == 0 ? bhp0 : 0.f, lhi == 0 ? bhp1 : 0.f, 0.f, 0.f};
#pragma unroll
      for (int kt = 0; kt < 4; ++kt) {
        bf16x8 wt = *(volatile const bf16x8*)&s_whp[kt * 512 + l * 8];
        ar = __builtin_amdgcn_mfma_f32_16x16x32_bf16(wt, BhN[Pt][kt], ar, 0,
                                                     0, 0);
      }
      if (lhi == 0) {
        f32x2 rv = {ar[0], ar[1]};
        *(f32x2*)&out[(size_t)t * (NPEDS * 2) +
                      (size_t)(pbase + Pt * 16 + llo) * 2] = rv;
      }
    }
  };

  // ---- transition 0: gates = w_hh*h0 + rank-2 lpr fold + b0eff ----
  {
    f32x2 lp0 = *(const f32x2*)&lpr[(size_t)ped0 * 2];
    f32x2 lp1 = *(const f32x2*)&lpr[(size_t)ped1 * 2];
    bf16x8 BhN[2][4];
    bf16x4 loT0, loT1;
#pragma unroll
    for (int c = 0; c < 8; ++c) {
      f32x4 acc0[4], acc1[4];
#pragma unroll
      for (int g = 0; g < 4; ++g) {
        int n0 = g * HD + c * 16 + lhi * 4;
        f32x4 b0 = *(const f32x4*)&fl[512 + n0];
        f32x4 wa = *(const f32x4*)&fl[1024 + 2 * n0];
        f32x4 wb = *(const f32x4*)&fl[1024 + 2 * n0 + 4];
        f32x4 ci0, ci1;
        ci0[0] = b0[0] + wa[0] * lp0[0] + wa[1] * lp0[1];
        ci0[1] = b0[1] + wa[2] * lp0[0] + wa[3] * lp0[1];
        ci0[2] = b0[2] + wb[0] * lp0[0] + wb[1] * lp0[1];
        ci0[3] = b0[3] + wb[2] * lp0[0] + wb[3] * lp0[1];
        ci1[0] = b0[0] + wa[0] * lp1[0] + wa[1] * lp1[1];
        ci1[1] = b0[1] + wa[2] * lp1[0] + wa[3] * lp1[1];
        ci1[2] = b0[2] + wb[0] * lp1[0] + wb[1] * lp1[1];
        ci1[3] = b0[3] + wb[2] * lp1[0] + wb[3] * lp1[1];
        bf16x8 Wf =
            *(volatile const bf16x8*)&s_w[((c * 4 + g) * 4 + 0) * 512 + l * 8];
        acc0[g] = __builtin_amdgcn_mfma_f32_16x16x32_bf16(Wf, Bh[0][0], ci0,
                                                          0, 0, 0);
        acc1[g] = __builtin_amdgcn_mfma_f32_16x16x32_bf16(Wf, Bh[1][0], ci1,
                                                          0, 0, 0);
      }
#pragma unroll
      for (int kt = 1; kt < 4; ++kt)
#pragma unroll
        for (int g = 0; g < 4; ++g) {
          bf16x8 Wf = *(volatile const bf16x8*)&s_w[((c * 4 + g) * 4 + kt) *
                                                        512 + l * 8];
          acc0[g] = __builtin_amdgcn_mfma_f32_16x16x32_bf16(Wf, Bh[0][kt],
                                                            acc0[g], 0, 0, 0);
          acc1[g] = __builtin_amdgcn_mfma_f32_16x16x32_bf16(Wf, Bh[1][kt],
                                                            acc1[g], 0, 0, 0);
        }
      bf16x4 h40 = nonlin(acc0, creg[0][c]);
      bf16x4 h41 = nonlin(acc1, creg[1][c]);
      if (c & 1) {
        BhN[0][c >> 1] =
            __builtin_shufflevector(loT0, h40, 0, 1, 2, 3, 4, 5, 6, 7);
        BhN[1][c >> 1] =
            __builtin_shufflevector(loT1, h41, 0, 1, 2, 3, 4, 5, 6, 7);
      } else {
        loT0 = h40;
        loT1 = h41;
      }
    }
    rel_do(BhN, 0);
#pragma unroll
    for (int Pt = 0; Pt < 2; ++Pt)
#pragma unroll
      for (int kt = 0; kt < 4; ++kt) Bh[Pt][kt] = BhN[Pt][kt];
  }
  __syncthreads();
  // restage s_w with W_eff fragments
  {
    const f32x4* src = (const f32x4*)(wsB + (size_t)WHH_FRAGS * 512);
    f32x4* dst = (f32x4*)s_w;
#pragma unroll
    for (int i = 0; i < 16; ++i) dst[i * 512 + tid] = src[i * 512 + tid];
  }
  __syncthreads();

  // ---- transitions 1..11: NO barriers; h/c in regs, weights from LDS ----
#pragma unroll 1
  for (int t = 1; t < SEQ; ++t) {
    bf16x8 BhN[2][4];
    bf16x4 loT0, loT1;
#pragma unroll
    for (int c = 0; c < 8; ++c) {
      f32x4 acc0[4], acc1[4];
#pragma unroll
      for (int g = 0; g < 4; ++g) {
        f32x4 ci =
            *(volatile const f32x4*)&s_beff[g * HD + c * 16 + lhi * 4];
        bf16x8 Wf =
            *(volatile const bf16x8*)&s_w[((c * 4 + g) * 4 + 0) * 512 + l * 8];
        acc0[g] = __builtin_amdgcn_mfma_f32_16x16x32_bf16(Wf, Bh[0][0], ci, 0,
                                                          0, 0);
        acc1[g] = __builtin_amdgcn_mfma_f32_16x16x32_bf16(Wf, Bh[1][0], ci, 0,
                                                          0, 0);
      }
#pragma unroll
      for (int kt = 1; kt < 4; ++kt)
#pragma unroll
        for (int g = 0; g < 4; ++g) {
          bf16x8 Wf = *(volatile const bf16x8*)&s_w[((c * 4 + g) * 4 + kt) *
                                                        512 + l * 8];
          acc0[g] = __builtin_amdgcn_mfma_f32_16x16x32_bf16(Wf, Bh[0][kt],
                                                            acc0[g], 0, 0, 0);
          acc1[g] = __builtin_amdgcn_mfma_f32_16x16x32_bf16(Wf, Bh[1][kt],
                                                            acc1[g], 0, 0, 0);
        }
      bf16x4 h40 = nonlin(acc0, creg[0][c]);
      bf16x4 h41 = nonlin(acc1, creg[1][c]);
      if (c & 1) {
        BhN[0][c >> 1] =
            __builtin_shufflevector(loT0, h40, 0, 1, 2, 3, 4, 5, 6, 7);
        BhN[1][c >> 1] =
            __builtin_shufflevector(loT1, h41, 0, 1, 2, 3, 4, 5, 6, 7);
      } else {
        loT0 = h40;
        loT1 = h41;
      }
    }
    rel_do(BhN, t);
#pragma unroll
    for (int Pt = 0; Pt < 2; ++Pt)
#pragma unroll
      for (int kt = 0; kt < 4; ++kt) Bh[Pt][kt] = BhN[Pt][kt];
  }
}

extern "C" void kernel_launch(void* const* d_in, const int* in_sizes, int n_in,
                              void* d_out, int out_size, void* d_ws,
                              size_t ws_size, hipStream_t stream) {
  // setup_inputs order:
  // 0 last_pos (unused), 1 last_pos_rel, 2 h0, 3 c0, 4 w_ih, 5 w_hh,
  // 6 b_ih, 7 b_hh, 8 w_se, 9 b_se, 10 w_hp, 11 b_hp
  const float* lpr = (const float*)d_in[1];
  const float* h0 = (const float*)d_in[2];
  const float* c0 = (const float*)d_in[3];
  const float* w_ih = (const float*)d_in[4];
  const float* w_hh = (const float*)d_in[5];
  const float* b_ih = (const float*)d_in[6];
  const float* b_hh = (const float*)d_in[7];
  const float* w_se = (const float*)d_in[8];
  const float* b_se = (const float*)d_in[9];
  const float* w_hp = (const float*)d_in[10];
  const float* b_hp = (const float*)d_in[11];
  short* wsB = (short*)d_ws;  // frags 266240 B + float tail 8192 B = 274432 B
  float* fl = (float*)((char*)d_ws + (size_t)NFRAGS * 512 * sizeof(short));
  float* out = (float*)d_out;

  prep_kernel<<<67, 256, 0, stream>>>(w_ih, w_hh, w_se, w_hp, b_ih, b_hh,
                                      b_se, b_hp, wsB, fl);
  lstm_kernel<<<NPEDS / MBLK, 512, 0, stream>>>(lpr, h0, c0, b_hp, wsB, fl,
                                                out);
}

// Round 12
// 404.605 us; speedup vs baseline: 1.7385x; 1.7385x over previous
//
#include <hip/hip_runtime.h>
#include <hip/hip_bf16.h>

typedef __attribute__((ext_vector_type(8))) short bf16x8;
typedef __attribute__((ext_vector_type(4))) short bf16x4;
typedef __attribute__((ext_vector_type(4))) float f32x4;

#define NPEDS 65536
#define SEQ 12
#define HD 128
#define ED 64
#define MBLK 64
#define P1 136  // h-row pitch in elems (272 B, 16B-aligned rows)
#define WHH_FRAGS 128
#define WEFF_FRAGS 132  // 128 gate frags + 4 w_hp frags
#define NFRAGS (WHH_FRAGS + WEFF_FRAGS)
#define L2E 1.44269504088896340736f
#define NEG2L (-2.88539008177792681472f)
// float tail after frags: beff[512], b0eff[512], w2[1024]

__device__ __forceinline__ short f2bf(float x) {
  __hip_bfloat16 b = __float2bfloat16(x);  // RNE
  return __builtin_bit_cast(short, b);
}
__device__ __forceinline__ float exp2_(float x) {
#if __has_builtin(__builtin_amdgcn_exp2f)
  return __builtin_amdgcn_exp2f(x);
#else
  return exp2f(x);
#endif
}

// Physical elem position of logical 4-elem k-group a=k>>2 within a row
// (fragment-contiguous layout): lane (llo,lhi), K-tile kt reads 8 contiguous
// elems at kt*32 + lhi*8, giving k = kt*32 + lhi*4 + (e&3) + (e>>2)*16.
__device__ __forceinline__ int pe_grp(int a) {
  return (a >> 3) * 32 + (a & 3) * 8 + ((a >> 2) & 1) * 4;
}

// Gate rows PRE-SCALED by log2e (2*log2e for gate g; torch order i,f,g,o):
// sigm(x)=rcp(1+exp2(-y)); tanh(g)=(2-R)/R, R=1+exp2(-yg).
// wsB layout (shorts):
//  [0, 128*512):         step-0 frags (w_hh, scaled), frag = (cc*4+g)*4+kt
//  [128*512, 256*512):   W_eff gate frags (scaled),   frag = (cc*4+g)*4+kt
//  [256*512, 260*512):   w_hp rel frags (UNscaled),   frag = kt
//  float tail fl[]: fl[0:512) beff, fl[512:1024) b0eff, fl[1024:2048) w2[n][2]
__global__ void prep_kernel(const float* __restrict__ w_ih,
                            const float* __restrict__ w_hh,
                            const float* __restrict__ w_se,
                            const float* __restrict__ w_hp,
                            const float* __restrict__ b_ih,
                            const float* __restrict__ b_hh,
                            const float* __restrict__ b_se,
                            const float* __restrict__ b_hp,
                            short* __restrict__ wsB, float* __restrict__ fl) {
  int t = blockIdx.x * 256 + threadIdx.x;
  if (t < WHH_FRAGS * 64) {
    int frag = t >> 6, l = t & 63;
    int cc = frag >> 4, g = (frag >> 2) & 3, kt = frag & 3;
    float fac = (g == 2) ? 2.0f * L2E : L2E;
    int n = g * HD + cc * 16 + (l & 15);
    bf16x8 v;
#pragma unroll
    for (int e = 0; e < 8; ++e) {
      int k = kt * 32 + ((l >> 4) << 2) + (e & 3) + ((e >> 2) << 4);
      v[e] = f2bf(w_hh[n * HD + k] * fac);
    }
    *(bf16x8*)(wsB + (size_t)frag * 512 + l * 8) = v;
  } else if (t < NFRAGS * 64) {
    int u = t - WHH_FRAGS * 64;
    int frag = u >> 6, l = u & 63;
    int llo = l & 15;
    int ks[8];
#pragma unroll
    for (int e = 0; e < 8; ++e)
      ks[e] = (frag & 3) * 32 + ((l >> 4) << 2) + (e & 3) + ((e >> 2) << 4);
    float acc[8];
    if (frag < 128) {
      int cc = frag >> 4, g = (frag >> 2) & 3;
      float fac = (g == 2) ? 2.0f * L2E : L2E;
      int n = g * HD + cc * 16 + llo;
#pragma unroll
      for (int e = 0; e < 8; ++e) acc[e] = w_hh[n * HD + ks[e]];
      for (int j = 0; j < ED; ++j) {
        float wij = w_ih[n * ED + j];
        float se0 = w_se[2 * j], se1 = w_se[2 * j + 1];
#pragma unroll
        for (int e = 0; e < 8; ++e)
          acc[e] += wij * (se0 * w_hp[ks[e]] + se1 * w_hp[HD + ks[e]]);
      }
#pragma unroll
      for (int e = 0; e < 8; ++e) acc[e] *= fac;
    } else {
#pragma unroll
      for (int e = 0; e < 8; ++e)
        acc[e] = (llo < 2) ? w_hp[llo * HD + ks[e]] : 0.f;
    }
    bf16x8 v;
#pragma unroll
    for (int e = 0; e < 8; ++e) v[e] = f2bf(acc[e]);
    *(bf16x8*)(wsB + (size_t)(WHH_FRAGS + frag) * 512 + l * 8) = v;
  } else if (t < NFRAGS * 64 + 512) {
    int n = t - NFRAGS * 64;
    float fac = ((n >> 7) == 2) ? 2.0f * L2E : L2E;
    float b = b_ih[n] + b_hh[n];
    float s0 = 0.f, w20 = 0.f, w21 = 0.f;
    for (int j = 0; j < ED; ++j) {
      float wij = w_ih[n * ED + j];
      s0 += wij * b_se[j];
      w20 += wij * w_se[2 * j];
      w21 += wij * w_se[2 * j + 1];
    }
    fl[n] = fac * (b + s0 + w20 * b_hp[0] + w21 * b_hp[1]);  // beff (s>=1)
    fl[512 + n] = fac * (b + s0);                            // b0eff (step 0)
    fl[1024 + 2 * n] = fac * w20;  // w2 = w_ih @ w_se (scaled)
    fl[1024 + 2 * n + 1] = fac * w21;
  }
}

// 256-THREAD / 4-WAVE BLOCKS for multi-block residency: at the fixed
// ~2-waves/SIMD register budget, two (LDS permitting three) independent
// 4-wave blocks co-reside per CU; their private barriers interleave, so
// one block's compute hides the other's barrier drain + LDS latency.
// Each wave owns TWO 16-col chunks (cc = w, w+4); Af fragments are loaded
// once per M-tile and shared by both chunks and the fused rel (Mt == w).
// B-fragments stream from global/L2 (volatile + unroll-1 blocks LICM from
// rematerializing a 128-reg weight file -- the R10/R11 failure mode).
__global__ __launch_bounds__(256, 2) void lstm_kernel(
    const float* __restrict__ lpr, const float* __restrict__ h0,
    const float* __restrict__ c0, const float* __restrict__ b_hp,
    const short* __restrict__ wsB, const float* __restrict__ fl,
    float* __restrict__ out) {
  __shared__ __align__(16) short hb[2][MBLK * P1];  // 34 KB
  __shared__ __align__(16) short s_wsR[4 * 512];    // 4 KB w_hp frags
  __shared__ float s_beff[512];                     // 2 KB folded bias
  __shared__ float s_lpr[MBLK * 2];                 // 0.5 KB

  const int tid = threadIdx.x;
  const int w = tid >> 6;  // wave id 0..3
  const int l = tid & 63;
  const int lhi = l >> 4;
  const int llo = l & 15;
  const int p0 = blockIdx.x * MBLK;
  // two col-chunks per wave; pe-layout h-offsets (hof1 = hof0 + 64)
  const int hof0 = (w >> 1) * 32 + (llo >> 2) * 8 + (w & 1) * 4 + (llo & 3);
  const int hof1 = hof0 + 64;

  if (tid < 128) s_lpr[tid] = lpr[(size_t)p0 * 2 + tid];
  s_beff[tid] = fl[tid];
  s_beff[tid + 256] = fl[tid + 256];
  {
    const unsigned long long* src =
        (const unsigned long long*)(wsB + (size_t)(WHH_FRAGS + 128) * 512);
    ((unsigned long long*)s_wsR)[tid] = src[tid];
    ((unsigned long long*)s_wsR)[tid + 256] = src[tid + 256];
  }

  // c0 -> registers: creg[cci][Mt][r], chunk cc = w + cci*4
  float creg[2][4][4];
#pragma unroll
  for (int cci = 0; cci < 2; ++cci)
#pragma unroll
    for (int Mt = 0; Mt < 4; ++Mt)
#pragma unroll
      for (int r = 0; r < 4; ++r)
        creg[cci][Mt][r] = c0[(size_t)(p0 + Mt * 16 + lhi * 4 + r) * HD +
                              (w + cci * 4) * 16 + llo];

  const float bhp_l = (llo < 2) ? b_hp[llo] : 0.f;

  // stage h0 -> hb[0] (pe layout): 2048 groups of 4 elems, 8 iters
#pragma unroll
  for (int i = 0; i < 8; ++i) {
    int grp = i * 256 + tid;
    int p = grp >> 5, a = grp & 31;
    f32x4 v = *(const f32x4*)(h0 + (size_t)(p0 + p) * HD + a * 4);
    bf16x4 s;
    s[0] = f2bf(v[0]); s[1] = f2bf(v[1]); s[2] = f2bf(v[2]); s[3] = f2bf(v[3]);
    *(bf16x4*)(&hb[0][p * P1 + pe_grp(a)]) = s;
  }
  __syncthreads();

  // 7-trans nonlinearity (gates pre-scaled): writes h to An at hof
  auto update_mt = [&](f32x4 (&acc)[4], float (&cr)[4], int rowb, short* An,
                       int hof) {
#pragma unroll
    for (int r = 0; r < 4; ++r) {
      float yi = acc[0][r], yf = acc[1][r];
      float yg = acc[2][r], yo = acc[3][r];
      float P = 1.f + exp2_(-yf);
      float Q = 1.f + exp2_(-yi);
      float R = 1.f + exp2_(-yg);
      float QR = Q * R;
      float rD = __builtin_amdgcn_rcpf(P * QR);
      float cn = (cr[r] * QR + (2.f - R) * P) * rD;
      cr[r] = cn;
      float T = 1.f + exp2_(cn * NEG2L);
      float S = 1.f + exp2_(-yo);
      float hn = (2.f - T) * __builtin_amdgcn_rcpf(S * T);
      An[(rowb + r) * P1 + hof] = f2bf(hn);
    }
  };

  auto load_af = [&](bf16x8 (&Af)[4], const short* A, int Mt) {
#pragma unroll
    for (int kt = 0; kt < 4; ++kt)
      Af[kt] = *(const bf16x8*)(&A[(Mt * 16 + llo) * P1 + kt * 32 + lhi * 8]);
  };
  // gate chain for chunk cc; B-frags streamed volatile from global (L2)
  auto gates = [&](f32x4 (&acc)[4], bf16x8 (&Af)[4], int cc,
                   const short* wsrc) {
#pragma unroll
    for (int g = 0; g < 4; ++g) {
      float b = s_beff[g * HD + cc * 16 + llo];
      acc[g] = {b, b, b, b};
    }
#pragma unroll
    for (int kt = 0; kt < 4; ++kt)
#pragma unroll
      for (int g = 0; g < 4; ++g) {
        bf16x8 Bf = *(volatile const bf16x8*)(wsrc +
                        (size_t)((cc * 4 + g) * 4 + kt) * 512 + l * 8);
        acc[g] = __builtin_amdgcn_mfma_f32_16x16x32_bf16(Af[kt], Bf, acc[g],
                                                         0, 0, 0);
      }
  };
  // rel for M-tile Mt == w, using already-loaded Af
  auto rel_do = [&](bf16x8 (&Af)[4], int sout) {
    f32x4 ar = {bhp_l, bhp_l, bhp_l, bhp_l};
#pragma unroll
    for (int kt = 0; kt < 4; ++kt) {
      bf16x8 wt = *(volatile const bf16x8*)(s_wsR + kt * 512 + l * 8);
      ar = __builtin_amdgcn_mfma_f32_16x16x32_bf16(Af[kt], wt, ar, 0, 0, 0);
    }
    if (llo < 2) {
#pragma unroll
      for (int r = 0; r < 4; ++r)
        out[(size_t)sout * (NPEDS * 2) +
            (size_t)(p0 + w * 16 + lhi * 4 + r) * 2 + llo] = ar[r];
    }
  };

  // ---- step 0: gates = h0 @ w_hh.T + lpr @ w2.T + b0eff (rank-2 fold) ----
  {
    float b0r[2][4], w20r[2][4], w21r[2][4];
#pragma unroll
    for (int cci = 0; cci < 2; ++cci)
#pragma unroll
      for (int g = 0; g < 4; ++g) {
        int n0 = g * HD + (w + cci * 4) * 16 + llo;
        b0r[cci][g] = fl[512 + n0];
        w20r[cci][g] = fl[1024 + 2 * n0];
        w21r[cci][g] = fl[1024 + 2 * n0 + 1];
      }
#pragma unroll
    for (int Mt = 0; Mt < 4; ++Mt) {
      bf16x8 Af[4];
      load_af(Af, hb[0], Mt);
#pragma unroll
      for (int cci = 0; cci < 2; ++cci) {
        int cc = w + cci * 4;
        f32x4 acc[4];
#pragma unroll
        for (int g = 0; g < 4; ++g)
#pragma unroll
          for (int r = 0; r < 4; ++r) {
            int row = Mt * 16 + lhi * 4 + r;
            acc[g][r] = b0r[cci][g] + w20r[cci][g] * s_lpr[row * 2] +
                        w21r[cci][g] * s_lpr[row * 2 + 1];
          }
#pragma unroll
        for (int kt = 0; kt < 4; ++kt)
#pragma unroll
          for (int g = 0; g < 4; ++g) {
            bf16x8 Bf = *(volatile const bf16x8*)(wsB +
                            (size_t)((cc * 4 + g) * 4 + kt) * 512 + l * 8);
            acc[g] = __builtin_amdgcn_mfma_f32_16x16x32_bf16(Af[kt], Bf,
                                                             acc[g], 0, 0, 0);
          }
        update_mt(acc, creg[cci][Mt], Mt * 16 + lhi * 4, hb[1],
                  cci ? hof1 : hof0);
      }
    }
    __syncthreads();
  }

  // ---- steps 1..11: gates = h @ W_eff.T + beff; rel(s-1) fused at Mt==w ----
  const short* wsW = wsB + (size_t)WHH_FRAGS * 512;
#pragma unroll 1
  for (int s = 1; s < SEQ; ++s) {
    const short* A = hb[s & 1];
    short* An = hb[(s + 1) & 1];
#pragma unroll
    for (int Mt = 0; Mt < 4; ++Mt) {
      bf16x8 Af[4];
      load_af(Af, A, Mt);
      f32x4 acc[4];
      gates(acc, Af, w, wsW);
      if (Mt == w) rel_do(Af, s - 1);
      update_mt(acc, creg[0][Mt], Mt * 16 + lhi * 4, An, hof0);
      gates(acc, Af, w + 4, wsW);
      update_mt(acc, creg[1][Mt], Mt * 16 + lhi * 4, An, hof1);
    }
    __syncthreads();
  }

  // ---- epilogue: rel(11) from h(12) in hb[SEQ & 1] == hb[0] ----
  {
    bf16x8 Af[4];
    load_af(Af, hb[SEQ & 1], w);
    rel_do(Af, SEQ - 1);
  }
}

extern "C" void kernel_launch(void* const* d_in, const int* in_sizes, int n_in,
                              void* d_out, int out_size, void* d_ws,
                              size_t ws_size, hipStream_t stream) {
  // setup_inputs order:
  // 0 last_pos (unused), 1 last_pos_rel, 2 h0, 3 c0, 4 w_ih, 5 w_hh,
  // 6 b_ih, 7 b_hh, 8 w_se, 9 b_se, 10 w_hp, 11 b_hp
  const float* lpr = (const float*)d_in[1];
  const float* h0 = (const float*)d_in[2];
  const float* c0 = (const float*)d_in[3];
  const float* w_ih = (const float*)d_in[4];
  const float* w_hh = (const float*)d_in[5];
  const float* b_ih = (const float*)d_in[6];
  const float* b_hh = (const float*)d_in[7];
  const float* w_se = (const float*)d_in[8];
  const float* b_se = (const float*)d_in[9];
  const float* w_hp = (const float*)d_in[10];
  const float* b_hp = (const float*)d_in[11];
  short* wsB = (short*)d_ws;  // frags 266240 B + float tail 8192 B = 274432 B
  float* fl = (float*)((char*)d_ws + (size_t)NFRAGS * 512 * sizeof(short));
  float* out = (float*)d_out;

  prep_kernel<<<67, 256, 0, stream>>>(w_ih, w_hh, w_se, w_hp, b_ih, b_hh,
                                      b_se, b_hp, wsB, fl);
  lstm_kernel<<<NPEDS / MBLK, 256, 0, stream>>>(lpr, h0, c0, b_hp, wsB, fl,
                                                out);
}